// Round 1
// 394.203 us; speedup vs baseline: 1.0957x; 1.0957x over previous
//
#include <hip/hip_runtime.h>

#define D 384
#define D4 96      // D / 4
#define SLOTS 96   // max degree bucket; dst ~ Poisson(16), P(deg>96) ~ 0

typedef float vfloat4 __attribute__((ext_vector_type(4)));

// ---------------------------------------------------------------------------
// Kernel 1 (fused): block-level q-norm + per-edge cosine sim + bucket scatter.
// 4 edges per WAVE (16 per 256-thread block). Edges are processed in pairs:
// two consecutive ea rows form a contiguous span of 192 float4s = exactly
// 3 float4s per lane, so all 64 lanes are fully used and each lane has
// 6 x 16B loads in flight per wave (vs 1.5 before) -> latency hidden.
// sim = (v.q_raw) / (|v||q|).
// ---------------------------------------------------------------------------
__global__ __launch_bounds__(256) void edge_kernel(
        const float* __restrict__ ea, const float* __restrict__ q,
        const int* __restrict__ src, const int* __restrict__ dst,
        int* __restrict__ cnt, int2* __restrict__ bucket, int E) {
    __shared__ float s_q[D];
    __shared__ float s_red[4];
    __shared__ float s_invq;
    int t = threadIdx.x;

    // stage q raw + block-reduce sum of squares (redundant per block; ~free,
    // and now amortized over 16 edges/block instead of 4)
    float ssq = 0.f;
    for (int i = t; i < D; i += 256) { float v = q[i]; s_q[i] = v; ssq += v * v; }
    for (int s = 32; s > 0; s >>= 1) ssq += __shfl_down(ssq, s);
    if ((t & 63) == 0) s_red[t >> 6] = ssq;
    __syncthreads();
    if (t == 0)
        s_invq = 1.0f / fmaxf(sqrtf(s_red[0] + s_red[1] + s_red[2] + s_red[3]), 1e-12f);
    __syncthreads();

    int wave = t >> 6, lane = t & 63;
    int e0 = (blockIdx.x * 4 + wave) * 4;   // 4 edges per wave (2 pairs)
    if (e0 >= E) return;

    const vfloat4* q4 = (const vfloat4*)s_q;
    bool lo = lane < 32;

    if (e0 + 4 <= E) {
        // ---- fast path: 2 full pairs ----
        // chunk->q mapping within a 2-row span (float4 index i = lane + 64*j):
        //   c0: i = lane        -> edge A, q4[lane]
        //   c1: i = lane+64     -> lane<32: edge A, q4[lane+64]; else edge B, q4[lane-32]
        //   c2: i = lane+128    -> edge B, q4[lane+32]
        vfloat4 qc0 = q4[lane];
        vfloat4 qc1 = lo ? q4[lane + 64] : q4[lane - 32];
        vfloat4 qc2 = q4[lane + 32];

        const vfloat4* sp0 = (const vfloat4*)(ea + (size_t)e0 * D);        // rows e0, e0+1
        const vfloat4* sp1 = (const vfloat4*)(ea + (size_t)(e0 + 2) * D);  // rows e0+2, e0+3

        // issue all 6 streaming loads up front
        vfloat4 a0 = __builtin_nontemporal_load(&sp0[lane]);
        vfloat4 b0 = __builtin_nontemporal_load(&sp0[lane + 64]);
        vfloat4 c0 = __builtin_nontemporal_load(&sp0[lane + 128]);
        vfloat4 a1 = __builtin_nontemporal_load(&sp1[lane]);
        vfloat4 b1 = __builtin_nontemporal_load(&sp1[lane + 64]);
        vfloat4 c1 = __builtin_nontemporal_load(&sp1[lane + 128]);

        // pair 0 partials
        float dA0 = a0.x*qc0.x + a0.y*qc0.y + a0.z*qc0.z + a0.w*qc0.w;
        float sA0 = a0.x*a0.x + a0.y*a0.y + a0.z*a0.z + a0.w*a0.w;
        float db0 = b0.x*qc1.x + b0.y*qc1.y + b0.z*qc1.z + b0.w*qc1.w;
        float sb0 = b0.x*b0.x + b0.y*b0.y + b0.z*b0.z + b0.w*b0.w;
        float dB0 = c0.x*qc2.x + c0.y*qc2.y + c0.z*qc2.z + c0.w*qc2.w;
        float sB0 = c0.x*c0.x + c0.y*c0.y + c0.z*c0.z + c0.w*c0.w;
        if (lo) { dA0 += db0; sA0 += sb0; }
        else    { dB0 += db0; sB0 += sb0; }

        // pair 1 partials
        float dA1 = a1.x*qc0.x + a1.y*qc0.y + a1.z*qc0.z + a1.w*qc0.w;
        float sA1 = a1.x*a1.x + a1.y*a1.y + a1.z*a1.z + a1.w*a1.w;
        float db1 = b1.x*qc1.x + b1.y*qc1.y + b1.z*qc1.z + b1.w*qc1.w;
        float sb1 = b1.x*b1.x + b1.y*b1.y + b1.z*b1.z + b1.w*b1.w;
        float dB1 = c1.x*qc2.x + c1.y*qc2.y + c1.z*qc2.z + c1.w*qc2.w;
        float sB1 = c1.x*c1.x + c1.y*c1.y + c1.z*c1.z + c1.w*c1.w;
        if (lo) { dA1 += db1; sA1 += sb1; }
        else    { dB1 += db1; sB1 += sb1; }

        // 8 interleaved butterfly reductions (independent chains -> ILP)
        for (int s = 1; s < 64; s <<= 1) {
            dA0 += __shfl_xor(dA0, s); sA0 += __shfl_xor(sA0, s);
            dB0 += __shfl_xor(dB0, s); sB0 += __shfl_xor(sB0, s);
            dA1 += __shfl_xor(dA1, s); sA1 += __shfl_xor(sA1, s);
            dB1 += __shfl_xor(dB1, s); sB1 += __shfl_xor(sB1, s);
        }

        // lanes 0..3 each finish one edge (parallel atomics)
        if (lane < 4) {
            int e = e0 + lane;
            float dt = (lane == 0) ? dA0 : (lane == 1) ? dB0 : (lane == 2) ? dA1 : dB1;
            float s2 = (lane == 0) ? sA0 : (lane == 1) ? sB0 : (lane == 2) ? sA1 : sB1;
            float sim = dt * s_invq / fmaxf(sqrtf(s2), 1e-12f);
            int n = dst[e];
            int p = atomicAdd(&cnt[n], 1);
            if (p < SLOTS)  // never taken for this input; safety only
                bucket[(size_t)n * SLOTS + p] = make_int2(src[e], __float_as_int(sim));
        }
    } else {
        // ---- tail path (<4 edges left): old one-edge-per-wave scheme ----
        int ne = E - e0;
        for (int j = 0; j < ne; ++j) {
            const vfloat4* row = (const vfloat4*)(ea + (size_t)(e0 + j) * D);
            vfloat4 v = __builtin_nontemporal_load(&row[lane]);
            vfloat4 qq = q4[lane];
            float dot = v.x*qq.x + v.y*qq.y + v.z*qq.z + v.w*qq.w;
            float ss  = v.x*v.x + v.y*v.y + v.z*v.z + v.w*v.w;
            if (lo) {
                vfloat4 v2 = __builtin_nontemporal_load(&row[lane + 64]);
                vfloat4 q2 = q4[lane + 64];
                dot += v2.x*q2.x + v2.y*q2.y + v2.z*q2.z + v2.w*q2.w;
                ss  += v2.x*v2.x + v2.y*v2.y + v2.z*v2.z + v2.w*v2.w;
            }
            for (int s = 32; s > 0; s >>= 1) {
                dot += __shfl_down(dot, s);
                ss  += __shfl_down(ss, s);
            }
            if (lane == 0) {
                float sim = dot * s_invq / fmaxf(sqrtf(ss), 1e-12f);
                int n = dst[e0 + j];
                int p = atomicAdd(&cnt[n], 1);
                if (p < SLOTS)
                    bucket[(size_t)n * SLOTS + p] = make_int2(src[e0 + j], __float_as_int(sim));
            }
        }
    }
}

// ---------------------------------------------------------------------------
// Kernel 2: one layer. Block (384 thr) per node. 4 groups of 96 threads; group
// g handles edges k+g, thread r=t%96 owns float4 r of the row. 4-deep unroll
// -> 16 rows in flight per block (covers the whole deg~16 common case in one
// unrolled body -> one latency round instead of two dependent ones).
// x_out[n] = 0.5*x_in[n] + 0.5 * (sum_e x_in[src[e]]*sim[e]) / max(deg,1)
// ---------------------------------------------------------------------------
__global__ __launch_bounds__(D) void aggregate_kernel(
        const float* __restrict__ xin, const int* __restrict__ cnt,
        const int2* __restrict__ bucket, float* __restrict__ xout, int N) {
    int n = blockIdx.x;
    int t = threadIdx.x;
    int deg = cnt[n];               // uniform -> scalar load
    int m = min(deg, SLOTS);

    __shared__ int    s_src[SLOTS];
    __shared__ float  s_sim[SLOTS];
    __shared__ float4 s_red[4][D4];

    const float4* xin4 = (const float4*)xin;

    // issue the self-row load early (epilogue threads only) to hide latency
    float4 xi = make_float4(0.f, 0.f, 0.f, 0.f);
    if (t < D4) xi = xin4[(size_t)n * D4 + t];

    if (t < m) {
        int2 p = bucket[(size_t)n * SLOTS + t];
        s_src[t] = p.x;
        s_sim[t] = __int_as_float(p.y);
    }
    __syncthreads();

    int g = t / D4, r = t - g * D4;

    float4 a0 = make_float4(0.f, 0.f, 0.f, 0.f);
    float4 a1 = make_float4(0.f, 0.f, 0.f, 0.f);
    float4 a2 = make_float4(0.f, 0.f, 0.f, 0.f);
    float4 a3 = make_float4(0.f, 0.f, 0.f, 0.f);
    int k = g;
    for (; k + 12 < m; k += 16) {
        float4 v0 = xin4[(size_t)s_src[k]      * D4 + r];
        float4 v1 = xin4[(size_t)s_src[k + 4]  * D4 + r];
        float4 v2 = xin4[(size_t)s_src[k + 8]  * D4 + r];
        float4 v3 = xin4[(size_t)s_src[k + 12] * D4 + r];
        float w0 = s_sim[k], w1 = s_sim[k + 4], w2 = s_sim[k + 8], w3 = s_sim[k + 12];
        a0.x += v0.x*w0; a0.y += v0.y*w0; a0.z += v0.z*w0; a0.w += v0.w*w0;
        a1.x += v1.x*w1; a1.y += v1.y*w1; a1.z += v1.z*w1; a1.w += v1.w*w1;
        a2.x += v2.x*w2; a2.y += v2.y*w2; a2.z += v2.z*w2; a2.w += v2.w*w2;
        a3.x += v3.x*w3; a3.y += v3.y*w3; a3.z += v3.z*w3; a3.w += v3.w*w3;
    }
    for (; k < m; k += 4) {
        float4 v0 = xin4[(size_t)s_src[k] * D4 + r];
        float  w0 = s_sim[k];
        a0.x += v0.x*w0; a0.y += v0.y*w0; a0.z += v0.z*w0; a0.w += v0.w*w0;
    }
    a0.x += a1.x + a2.x + a3.x;
    a0.y += a1.y + a2.y + a3.y;
    a0.z += a1.z + a2.z + a3.z;
    a0.w += a1.w + a2.w + a3.w;
    s_red[g][r] = a0;
    __syncthreads();

    if (t < D4) {
        float4 acc;
        acc.x = s_red[0][t].x + s_red[1][t].x + s_red[2][t].x + s_red[3][t].x;
        acc.y = s_red[0][t].y + s_red[1][t].y + s_red[2][t].y + s_red[3][t].y;
        acc.z = s_red[0][t].z + s_red[1][t].z + s_red[2][t].z + s_red[3][t].z;
        acc.w = s_red[0][t].w + s_red[1][t].w + s_red[2][t].w + s_red[3][t].w;
        float scale = 0.5f / fmaxf((float)deg, 1.0f);
        float4 o;
        o.x = 0.5f*xi.x + acc.x*scale;
        o.y = 0.5f*xi.y + acc.y*scale;
        o.z = 0.5f*xi.z + acc.z*scale;
        o.w = 0.5f*xi.w + acc.w*scale;
        ((float4*)xout)[(size_t)n * D4 + t] = o;
    }
}

// ---------------------------------------------------------------------------
extern "C" void kernel_launch(void* const* d_in, const int* in_sizes, int n_in,
                              void* d_out, int out_size, void* d_ws, size_t ws_size,
                              hipStream_t stream) {
    const float* x   = (const float*)d_in[0];
    const int*   ei  = (const int*)d_in[1];
    const float* ea  = (const float*)d_in[2];
    const float* qe  = (const float*)d_in[3];

    const int N = in_sizes[0] / D;      // 10000
    const int E = in_sizes[1] / 2;      // 160000
    const int* src = ei;
    const int* dst = ei + E;

    char* w = (char*)d_ws;
    size_t off = 0;
    auto alloc = [&](size_t bytes) {
        char* p = w + off;
        off = (off + bytes + 255) & ~(size_t)255;
        return p;
    };
    int*   cnt    = (int*)  alloc((size_t)N * 4);
    int2*  bucket = (int2*) alloc((size_t)N * SLOTS * 8);
    float* xbuf   = (float*)alloc((size_t)N * D * 4);
    (void)ws_size; (void)n_in; (void)out_size;

    (void)hipMemsetAsync(cnt, 0, (size_t)N * 4, stream);
    edge_kernel<<<(E + 15) / 16, 256, 0, stream>>>(ea, qe, src, dst, cnt, bucket, E);
    aggregate_kernel<<<N, D, 0, stream>>>(x, cnt, bucket, xbuf, N);
    aggregate_kernel<<<N, D, 0, stream>>>(xbuf, cnt, bucket, (float*)d_out, N);
}